// Round 3
// baseline (939.002 us; speedup 1.0000x reference)
//
#include <hip/hip_runtime.h>

#define DIN   128
#define DMID  256
#define DOUT  128
#define VNUM  50000

typedef __attribute__((ext_vector_type(8))) __bf16 bf16x8;
typedef __attribute__((ext_vector_type(4))) float  f32x4;

// ---- order-preserving monotone maps ----
static __device__ __forceinline__ unsigned unflip_bits(unsigned m) {
  unsigned mask = ((int)m < 0) ? 0x80000000u : 0xFFFFFFFFu;
  return m ^ mask;
}
// bf16 bits -> flipped u16 (monotone in float order)
static __device__ __forceinline__ unsigned short flip16(unsigned short b) {
  return b ^ (unsigned short)(((short)b >> 15) | 0x8000);
}
// flipped u16 -> flipped u32 of same bf16 widened to f32
static __device__ __forceinline__ unsigned flip32_from16(unsigned short m) {
  return ((unsigned)m << 16) | ((m & 0x8000u) ? 0u : 0xFFFFu);
}
// f32 bits -> bf16 bits, round-to-nearest-even
static __device__ __forceinline__ unsigned short f2b_bits(unsigned b) {
  return (unsigned short)((b + 0x7FFFu + ((b >> 16) & 1u)) >> 16);
}
static __device__ __forceinline__ unsigned short f2b(float f) {
  return f2b_bits(__float_as_uint(f));
}
// f32 max value -> flipped u32 encoding of bf16-rounded value
static __device__ __forceinline__ unsigned enc_max(float m) {
  return flip32_from16(flip16(f2b(m)));
}

// ---------------------------------------------------------------------------
// Sort machinery
// ---------------------------------------------------------------------------
__global__ void k_hist(const int* __restrict__ vid, int* __restrict__ counts, int E) {
  int i = blockIdx.x * blockDim.x + threadIdx.x;
  if (i < E) atomicAdd(counts + vid[i], 1);
}

__global__ __launch_bounds__(1024) void k_scan(int* __restrict__ cursor, int V) {
  __shared__ int wsum[16];
  const int tid = threadIdx.x, lane = tid & 63, wv = tid >> 6;
  int carry = 0;
  for (int base = 0; base < V; base += 1024) {
    const int idx = base + tid;
    const int c = (idx < V) ? cursor[idx] : 0;
    int s = c;
#pragma unroll
    for (int d = 1; d < 64; d <<= 1) {
      int t = __shfl_up(s, d, 64);
      if (lane >= d) s += t;
    }
    if (lane == 63) wsum[wv] = s;
    __syncthreads();
    if (wv == 0 && lane < 16) {
      int ws = wsum[lane];
#pragma unroll
      for (int d = 1; d < 16; d <<= 1) {
        int t = __shfl_up(ws, d, 16);
        if (lane >= d) ws += t;
      }
      wsum[lane] = ws;
    }
    __syncthreads();
    const int woff = (wv == 0) ? 0 : wsum[wv - 1];
    if (idx < V) cursor[idx] = carry + woff + (s - c);
    carry += wsum[15];
    __syncthreads();
  }
}

__global__ void k_scatter(const int* __restrict__ vid, int* __restrict__ cursor,
                          int* __restrict__ sorted, int E) {
  int i = blockIdx.x * blockDim.x + threadIdx.x;
  if (i < E) {
    int v = vid[i];
    int p = atomicAdd(cursor + v, 1);
    sorted[p] = i;
  }
}

// ---------------------------------------------------------------------------
// Kernel 1: GEMM1 over sorted edges + in-register segmented max.
// Pipelined: next tile's x rows prefetched into registers during MFMA+epilogue.
// ---------------------------------------------------------------------------
__global__ __launch_bounds__(256) void k_gemm1_max(
    const float* __restrict__ x, const int* __restrict__ vid,
    const int* __restrict__ sorted, const float* __restrict__ W1,
    const float* __restrict__ b1, unsigned* __restrict__ zu, int ntiles) {
  __shared__ unsigned short lx[64 * 136];
  __shared__ int lvid[64];

  const int tid  = threadIdx.x;
  const int lane = tid & 63;
  const int w    = tid >> 6;
  const int l15  = lane & 15;
  const int l4   = lane >> 4;
  const int row4 = tid >> 2;     // staging row (4 threads per row)
  const int q    = tid & 3;
  const int G    = gridDim.x;

  // W1 fragments + bias in registers (wave's 64-col slice)
  bf16x8 bfrag[4][4];
  float  bias[4];
#pragma unroll
  for (int ni = 0; ni < 4; ++ni) {
    const int col = w * 64 + ni * 16 + l15;
    bias[ni] = b1[col];
#pragma unroll
    for (int kk = 0; kk < 4; ++kk) {
      union { bf16x8 v; unsigned short u[8]; } tmp;
#pragma unroll
      for (int j = 0; j < 8; ++j)
        tmp.u[j] = f2b(W1[(kk * 32 + l4 * 8 + j) * DMID + col]);
      bfrag[kk][ni] = tmp.v;
    }
  }

  const int t0 = blockIdx.x;
  if (t0 >= ntiles) return;

  // ---- prologue: stage tile t0, prefetch ids for t0+G ----
  {
    const int eid = sorted[t0 * 64 + row4];
    const float4* src = reinterpret_cast<const float4*>(x + (size_t)eid * DIN + q * 32);
    unsigned short* dst = &lx[row4 * 136 + q * 32];
#pragma unroll
    for (int i = 0; i < 8; ++i) {
      float4 v = src[i];
      ushort4 o = { f2b(v.x), f2b(v.y), f2b(v.z), f2b(v.w) };
      *reinterpret_cast<ushort4*>(dst + i * 4) = o;
    }
    if (tid < 64) lvid[tid] = vid[sorted[t0 * 64 + tid]];
  }
  int tn0 = t0 + G; if (tn0 >= ntiles) tn0 = t0;
  int eidN   = sorted[tn0 * 64 + row4];
  int eidN64 = (tid < 64) ? sorted[tn0 * 64 + tid] : 0;
  __syncthreads();

  for (int t = t0; t < ntiles; t += G) {
    int tn = t + G; if (tn >= ntiles) tn = t;

    // ---- (a) issue prefetch: x rows of tile tn, vid of tile tn ----
    float4 xn[8];
    {
      const float4* src = reinterpret_cast<const float4*>(x + (size_t)eidN * DIN + q * 32);
#pragma unroll
      for (int i = 0; i < 8; ++i) xn[i] = src[i];
    }
    int vN = (tid < 64) ? vid[eidN64] : 0;

    // ---- (b) MFMA 64x64 per wave, K=128 ----
    f32x4 acc[4][4];
#pragma unroll
    for (int mi = 0; mi < 4; ++mi)
#pragma unroll
      for (int ni = 0; ni < 4; ++ni)
        acc[mi][ni] = (f32x4){bias[ni], bias[ni], bias[ni], bias[ni]};
#pragma unroll
    for (int kk = 0; kk < 4; ++kk) {
      bf16x8 a[4];
#pragma unroll
      for (int mi = 0; mi < 4; ++mi)
        a[mi] = *reinterpret_cast<const bf16x8*>(
            &lx[(mi * 16 + l15) * 136 + kk * 32 + l4 * 8]);
#pragma unroll
      for (int mi = 0; mi < 4; ++mi)
#pragma unroll
        for (int ni = 0; ni < 4; ++ni)
          acc[mi][ni] = __builtin_amdgcn_mfma_f32_16x16x32_bf16(
              a[mi], bfrag[kk][ni], acc[mi][ni], 0, 0, 0);
    }

    // ---- (c) in-register segmented max over vid runs ----
    {
      int rs = 0;
      while (rs < 64) {
        const int v = lvid[rs];
        int re = rs + 1;
        while (re < 64 && lvid[re] == v) ++re;

        float mx[4];
#pragma unroll
        for (int ni = 0; ni < 4; ++ni) mx[ni] = -3.4e38f;
#pragma unroll
        for (int mi = 0; mi < 4; ++mi)
#pragma unroll
          for (int r = 0; r < 4; ++r) {
            const int row = mi * 16 + l4 * 4 + r;
            const bool in = (row >= rs) && (row < re);
#pragma unroll
            for (int ni = 0; ni < 4; ++ni)
              mx[ni] = in ? fmaxf(mx[ni], acc[mi][ni][r]) : mx[ni];
          }
#pragma unroll
        for (int ni = 0; ni < 4; ++ni) {
          mx[ni] = fmaxf(mx[ni], __shfl_xor(mx[ni], 16));
          mx[ni] = fmaxf(mx[ni], __shfl_xor(mx[ni], 32));
        }
        const bool boundary = (rs == 0) || (re == 64);
        if (l4 == 0) {
          unsigned* base = zu + (size_t)v * DMID + w * 64 + l15;
#pragma unroll
          for (int ni = 0; ni < 4; ++ni) {
            const unsigned e = enc_max(mx[ni]);
            if (boundary) atomicMax(base + ni * 16, e);
            else          base[ni * 16] = e;
          }
        }
        rs = re;
      }
    }
    __syncthreads();

    // ---- (e) write prefetched tile to LDS; prefetch ids two tiles ahead ----
    {
      unsigned short* dst = &lx[row4 * 136 + q * 32];
#pragma unroll
      for (int i = 0; i < 8; ++i) {
        ushort4 o = { f2b(xn[i].x), f2b(xn[i].y), f2b(xn[i].z), f2b(xn[i].w) };
        *reinterpret_cast<ushort4*>(dst + i * 4) = o;
      }
      if (tid < 64) lvid[tid] = vN;
    }
    int t2 = tn + G; if (t2 >= ntiles) t2 = tn;
    eidN   = sorted[t2 * 64 + row4];
    eidN64 = (tid < 64) ? sorted[t2 * 64 + tid] : 0;
    __syncthreads();
  }
}

// ---------------------------------------------------------------------------
// Kernel Y: Y = unflip(zu) @ W2b  (V x 128). Block 256, wave 2x2.
// ---------------------------------------------------------------------------
__global__ __launch_bounds__(256) void k_ymm(
    const unsigned* __restrict__ zu, const float* __restrict__ W2,
    float* __restrict__ Y, int ntiles) {
  extern __shared__ unsigned short sm[];
  unsigned short* w2bt = sm;               // [128][264]
  unsigned short* za   = sm + 128 * 264;   // [64][264]

  const int tid  = threadIdx.x;
  const int lane = tid & 63;
  const int w    = tid >> 6;
  const int wr   = w >> 1, wc = w & 1;
  const int l15  = lane & 15, l4 = lane >> 4;

  {
    const int n = tid & 127, kh = tid >> 7;
    for (int k = kh * 128; k < kh * 128 + 128; ++k)
      w2bt[n * 264 + k] = f2b(W2[(size_t)(DIN + k) * DOUT + n]);
  }
  __syncthreads();

  for (int t = blockIdx.x; t < ntiles; t += gridDim.x) {
    {
      const int row = tid >> 2, q = tid & 3;
      const int v = t * 64 + row;
      unsigned short* dz = &za[row * 264 + q * 64];
      if (v < VNUM) {
        const uint4* sz = reinterpret_cast<const uint4*>(zu + (size_t)v * DMID + q * 64);
#pragma unroll
        for (int i = 0; i < 16; ++i) {
          uint4 m = sz[i];
          ushort4 o = { (unsigned short)(unflip_bits(m.x) >> 16),
                        (unsigned short)(unflip_bits(m.y) >> 16),
                        (unsigned short)(unflip_bits(m.z) >> 16),
                        (unsigned short)(unflip_bits(m.w) >> 16) };
          *reinterpret_cast<ushort4*>(dz + i * 4) = o;
        }
      } else {
        ushort4 zo = {0, 0, 0, 0};
#pragma unroll
        for (int i = 0; i < 16; ++i) *reinterpret_cast<ushort4*>(dz + i * 4) = zo;
      }
    }
    __syncthreads();

    f32x4 acc[2][4];
#pragma unroll
    for (int mi = 0; mi < 2; ++mi)
#pragma unroll
      for (int ni = 0; ni < 4; ++ni) acc[mi][ni] = (f32x4){0.f, 0.f, 0.f, 0.f};

#pragma unroll
    for (int kk = 0; kk < 8; ++kk) {
      bf16x8 a[2], b[4];
#pragma unroll
      for (int mi = 0; mi < 2; ++mi)
        a[mi] = *reinterpret_cast<const bf16x8*>(
            &za[(wr * 32 + mi * 16 + l15) * 264 + kk * 32 + l4 * 8]);
#pragma unroll
      for (int ni = 0; ni < 4; ++ni)
        b[ni] = *reinterpret_cast<const bf16x8*>(
            &w2bt[(wc * 64 + ni * 16 + l15) * 264 + kk * 32 + l4 * 8]);
#pragma unroll
      for (int mi = 0; mi < 2; ++mi)
#pragma unroll
        for (int ni = 0; ni < 4; ++ni)
          acc[mi][ni] = __builtin_amdgcn_mfma_f32_16x16x32_bf16(
              a[mi], b[ni], acc[mi][ni], 0, 0, 0);
    }

#pragma unroll
    for (int mi = 0; mi < 2; ++mi)
#pragma unroll
      for (int r = 0; r < 4; ++r) {
        const int v = t * 64 + wr * 32 + mi * 16 + l4 * 4 + r;
        if (v < VNUM) {
          float* o = Y + (size_t)v * DOUT + wc * 64 + l15;
#pragma unroll
          for (int ni = 0; ni < 4; ++ni) o[ni * 16] = acc[mi][ni][r];
        }
      }
    __syncthreads();
  }
}

// ---------------------------------------------------------------------------
// Kernel 2: out = x @ W2a + Y[vid]. Pipelined x prefetch + early Y gather.
// ---------------------------------------------------------------------------
__global__ __launch_bounds__(256) void k_gemm2(
    const float* __restrict__ x, const int* __restrict__ vid,
    const float* __restrict__ W2, const float* __restrict__ Y,
    float* __restrict__ out, int ntiles) {
  __shared__ unsigned short w2at[128 * 136];
  __shared__ unsigned short lx[64 * 136];
  __shared__ int lvid[64];

  const int tid  = threadIdx.x;
  const int lane = tid & 63;
  const int w    = tid >> 6;
  const int wr   = w >> 1, wc = w & 1;
  const int l15  = lane & 15, l4 = lane >> 4;
  const int row4 = tid >> 2, q = tid & 3;
  const int G    = gridDim.x;

  {
    const int n = tid & 127, kh = tid >> 7;
    for (int k = kh * 64; k < kh * 64 + 64; ++k)
      w2at[n * 136 + k] = f2b(W2[(size_t)k * DOUT + n]);
  }

  const int t0 = blockIdx.x;
  if (t0 >= ntiles) return;

  // prologue: load x regs for tile t0
  float4 xr[8];
  {
    const float4* src =
        reinterpret_cast<const float4*>(x + (size_t)(t0 * 64 + row4) * DIN + q * 32);
#pragma unroll
    for (int i = 0; i < 8; ++i) xr[i] = src[i];
  }
  int vOwn = (tid < 64) ? vid[t0 * 64 + tid] : 0;
  __syncthreads();  // w2at ready

  for (int t = t0; t < ntiles; t += G) {
    // ---- stage current tile from regs ----
    {
      unsigned short* dst = &lx[row4 * 136 + q * 32];
#pragma unroll
      for (int i = 0; i < 8; ++i) {
        ushort4 o = { f2b(xr[i].x), f2b(xr[i].y), f2b(xr[i].z), f2b(xr[i].w) };
        *reinterpret_cast<ushort4*>(dst + i * 4) = o;
      }
      if (tid < 64) lvid[tid] = vOwn;
    }
    __syncthreads();

    // ---- issue next-tile x prefetch ----
    int tn = t + G; if (tn >= ntiles) tn = t;
    {
      const float4* src =
          reinterpret_cast<const float4*>(x + (size_t)(tn * 64 + row4) * DIN + q * 32);
#pragma unroll
      for (int i = 0; i < 8; ++i) xr[i] = src[i];
    }
    vOwn = (tid < 64) ? vid[tn * 64 + tid] : 0;

    // ---- issue Y gathers for this tile ----
    float yv[2][4][4];  // [mi][r][ni]
#pragma unroll
    for (int mi = 0; mi < 2; ++mi)
#pragma unroll
      for (int r = 0; r < 4; ++r) {
        const int row = wr * 32 + mi * 16 + l4 * 4 + r;
        const float* Yr = Y + (size_t)lvid[row] * DOUT + wc * 64 + l15;
#pragma unroll
        for (int ni = 0; ni < 4; ++ni) yv[mi][r][ni] = Yr[ni * 16];
      }

    // ---- MFMA 32x64 per wave, K=128 ----
    f32x4 acc[2][4];
#pragma unroll
    for (int mi = 0; mi < 2; ++mi)
#pragma unroll
      for (int ni = 0; ni < 4; ++ni) acc[mi][ni] = (f32x4){0.f, 0.f, 0.f, 0.f};
#pragma unroll
    for (int kk = 0; kk < 4; ++kk) {
      bf16x8 a[2], b[4];
#pragma unroll
      for (int mi = 0; mi < 2; ++mi)
        a[mi] = *reinterpret_cast<const bf16x8*>(
            &lx[(wr * 32 + mi * 16 + l15) * 136 + kk * 32 + l4 * 8]);
#pragma unroll
      for (int ni = 0; ni < 4; ++ni)
        b[ni] = *reinterpret_cast<const bf16x8*>(
            &w2at[(wc * 64 + ni * 16 + l15) * 136 + kk * 32 + l4 * 8]);
#pragma unroll
      for (int mi = 0; mi < 2; ++mi)
#pragma unroll
        for (int ni = 0; ni < 4; ++ni)
          acc[mi][ni] = __builtin_amdgcn_mfma_f32_16x16x32_bf16(
              a[mi], b[ni], acc[mi][ni], 0, 0, 0);
    }

    // ---- epilogue: add Y, store ----
#pragma unroll
    for (int mi = 0; mi < 2; ++mi)
#pragma unroll
      for (int r = 0; r < 4; ++r) {
        const int row = wr * 32 + mi * 16 + l4 * 4 + r;
        float* o = out + (size_t)(t * 64 + row) * DOUT + wc * 64 + l15;
#pragma unroll
        for (int ni = 0; ni < 4; ++ni) o[ni * 16] = acc[mi][ni][r] + yv[mi][r][ni];
      }
    __syncthreads();
  }
}

// ---------------------------------------------------------------------------
extern "C" void kernel_launch(void* const* d_in, const int* in_sizes, int n_in,
                              void* d_out, int out_size, void* d_ws, size_t ws_size,
                              hipStream_t stream) {
  const float* x   = (const float*)d_in[0];
  const int*   vid = (const int*)d_in[1];
  const float* W1  = (const float*)d_in[2];
  const float* b1  = (const float*)d_in[3];
  const float* W2  = (const float*)d_in[4];
  float* out = (float*)d_out;

  const int E = in_sizes[1];      // 800000 (divisible by 64)
  const int ntiles = E / 64;
  const int ntY = (VNUM + 63) / 64;   // 782

  char* ws = (char*)d_ws;
  unsigned* zu = (unsigned*)ws;                                    // V*256 u32
  int* cnt     = (int*)(ws + (size_t)VNUM * DMID * 4);             // V
  int* sorted  = (int*)(ws + (size_t)VNUM * DMID * 4 + VNUM * 4);  // E
  float* Y     = (float*)(ws + (size_t)VNUM * DMID * 4 + VNUM * 4 + (size_t)E * 4);

  hipMemsetAsync(zu, 0, (size_t)VNUM * DMID * 4 + VNUM * 4, stream);

  k_hist<<<(E + 255) / 256, 256, 0, stream>>>(vid, cnt, E);
  k_scan<<<1, 1024, 0, stream>>>(cnt, VNUM);
  k_scatter<<<(E + 255) / 256, 256, 0, stream>>>(vid, cnt, sorted, E);

  k_gemm1_max<<<768, 256, 0, stream>>>(x, vid, sorted, W1, b1, zu, ntiles);

  const int smY = (128 * 264 + 64 * 264) * sizeof(unsigned short);
  hipFuncSetAttribute((const void*)k_ymm,
                      hipFuncAttributeMaxDynamicSharedMemorySize, smY);
  k_ymm<<<782, 256, smY, stream>>>(zu, W2, Y, ntY);

  k_gemm2<<<768, 256, 0, stream>>>(x, vid, W2, Y, out, ntiles);
}

// Round 4
// 694.552 us; speedup vs baseline: 1.3520x; 1.3520x over previous
//
#include <hip/hip_runtime.h>

#define DIN   128
#define DMID  256
#define DOUT  128
#define VNUM  50000

typedef __attribute__((ext_vector_type(8))) __bf16 bf16x8;
typedef __attribute__((ext_vector_type(4))) float  f32x4;

// ---- order-preserving monotone maps ----
static __device__ __forceinline__ unsigned unflip_bits(unsigned m) {
  unsigned mask = ((int)m < 0) ? 0x80000000u : 0xFFFFFFFFu;
  return m ^ mask;
}
static __device__ __forceinline__ unsigned short flip16(unsigned short b) {
  return b ^ (unsigned short)(((short)b >> 15) | 0x8000);
}
static __device__ __forceinline__ unsigned flip32_from16(unsigned short m) {
  return ((unsigned)m << 16) | ((m & 0x8000u) ? 0u : 0xFFFFu);
}
static __device__ __forceinline__ unsigned short f2b_bits(unsigned b) {
  return (unsigned short)((b + 0x7FFFu + ((b >> 16) & 1u)) >> 16);
}
static __device__ __forceinline__ unsigned short f2b(float f) {
  return f2b_bits(__float_as_uint(f));
}
static __device__ __forceinline__ unsigned enc_max(float m) {
  return flip32_from16(flip16(f2b(m)));
}

// ---------------------------------------------------------------------------
// Sort machinery
// ---------------------------------------------------------------------------
__global__ void k_hist(const int* __restrict__ vid, int* __restrict__ counts, int E) {
  int i = blockIdx.x * blockDim.x + threadIdx.x;
  if (i < E) atomicAdd(counts + vid[i], 1);
}

__global__ __launch_bounds__(1024) void k_scan(int* __restrict__ cursor, int V) {
  __shared__ int wsum[16];
  const int tid = threadIdx.x, lane = tid & 63, wv = tid >> 6;
  int carry = 0;
  for (int base = 0; base < V; base += 1024) {
    const int idx = base + tid;
    const int c = (idx < V) ? cursor[idx] : 0;
    int s = c;
#pragma unroll
    for (int d = 1; d < 64; d <<= 1) {
      int t = __shfl_up(s, d, 64);
      if (lane >= d) s += t;
    }
    if (lane == 63) wsum[wv] = s;
    __syncthreads();
    if (wv == 0 && lane < 16) {
      int ws = wsum[lane];
#pragma unroll
      for (int d = 1; d < 16; d <<= 1) {
        int t = __shfl_up(ws, d, 16);
        if (lane >= d) ws += t;
      }
      wsum[lane] = ws;
    }
    __syncthreads();
    const int woff = (wv == 0) ? 0 : wsum[wv - 1];
    if (idx < V) cursor[idx] = carry + woff + (s - c);
    carry += wsum[15];
    __syncthreads();
  }
}

__global__ void k_scatter(const int* __restrict__ vid, int* __restrict__ cursor,
                          int* __restrict__ sorted, int E) {
  int i = blockIdx.x * blockDim.x + threadIdx.x;
  if (i < E) {
    int v = vid[i];
    int p = atomicAdd(cursor + v, 1);
    sorted[p] = i;
  }
}

// ---------------------------------------------------------------------------
// Kernel 1: GEMM1 over sorted edges + ballot-based in-register segmented max.
// Block 512 (8 waves); wave w owns cols [w*32, w*32+32). Tile = 64 rows.
// ---------------------------------------------------------------------------
__global__ __launch_bounds__(512, 4) void k_gemm1_max(
    const float* __restrict__ x, const int* __restrict__ vid,
    const int* __restrict__ sorted, const float* __restrict__ W1,
    const float* __restrict__ b1, unsigned* __restrict__ zu, int ntiles) {
  __shared__ unsigned short lx[64 * 136];
  __shared__ int lvid[64];

  const int tid  = threadIdx.x;
  const int lane = tid & 63;
  const int w    = tid >> 6;       // 0..7
  const int l15  = lane & 15;
  const int l4   = lane >> 4;
  const int row8 = tid >> 3;       // staging: 8 threads per row
  const int s8   = tid & 7;        // 16 floats each

  // W1 fragments + bias for this wave's 32 cols
  bf16x8 bfrag[4][2];
  float  bias[2];
#pragma unroll
  for (int ni = 0; ni < 2; ++ni) {
    const int col = w * 32 + ni * 16 + l15;
    bias[ni] = b1[col];
#pragma unroll
    for (int kk = 0; kk < 4; ++kk) {
      union { bf16x8 v; unsigned short u[8]; } tmp;
#pragma unroll
      for (int j = 0; j < 8; ++j)
        tmp.u[j] = f2b(W1[(kk * 32 + l4 * 8 + j) * DMID + col]);
      bfrag[kk][ni] = tmp.v;
    }
  }

  for (int t = blockIdx.x; t < ntiles; t += gridDim.x) {
    // ---- stage x tile + vids ----
    if (tid < 64) lvid[tid] = vid[sorted[t * 64 + tid]];
    {
      const int eid = sorted[t * 64 + row8];
      const float4* src =
          reinterpret_cast<const float4*>(x + (size_t)eid * DIN + s8 * 16);
      unsigned short* dst = &lx[row8 * 136 + s8 * 16];
#pragma unroll
      for (int i = 0; i < 4; ++i) {
        float4 v = src[i];
        ushort4 o = { f2b(v.x), f2b(v.y), f2b(v.z), f2b(v.w) };
        *reinterpret_cast<ushort4*>(dst + i * 4) = o;
      }
    }
    __syncthreads();

    // ---- MFMA: 64 rows x 32 cols per wave, K=128 ----
    f32x4 acc[4][2];
#pragma unroll
    for (int mi = 0; mi < 4; ++mi)
#pragma unroll
      for (int ni = 0; ni < 2; ++ni)
        acc[mi][ni] = (f32x4){bias[ni], bias[ni], bias[ni], bias[ni]};
#pragma unroll
    for (int kk = 0; kk < 4; ++kk) {
      bf16x8 a[4];
#pragma unroll
      for (int mi = 0; mi < 4; ++mi)
        a[mi] = *reinterpret_cast<const bf16x8*>(
            &lx[(mi * 16 + l15) * 136 + kk * 32 + l4 * 8]);
#pragma unroll
      for (int mi = 0; mi < 4; ++mi)
#pragma unroll
        for (int ni = 0; ni < 2; ++ni)
          acc[mi][ni] = __builtin_amdgcn_mfma_f32_16x16x32_bf16(
              a[mi], bfrag[kk][ni], acc[mi][ni], 0, 0, 0);
    }

    // ---- ballot-based segmented max (no serial scans) ----
    {
      const int myv = lvid[lane];
      const int pv  = (lane == 0) ? ~myv : lvid[lane - 1];
      unsigned long long m = __ballot(myv != pv);   // run-start mask
      while (m) {
        const unsigned long long m2 = m & (m - 1);
        const int rs = (int)__builtin_ctzll(m);
        const int re = m2 ? (int)__builtin_ctzll(m2) : 64;

        float mx0 = -3.4e38f, mx1 = -3.4e38f;
#pragma unroll
        for (int mi = 0; mi < 4; ++mi)
#pragma unroll
          for (int r = 0; r < 4; ++r) {
            const int row = mi * 16 + l4 * 4 + r;
            const bool in = (row >= rs) && (row < re);
            mx0 = in ? fmaxf(mx0, acc[mi][0][r]) : mx0;
            mx1 = in ? fmaxf(mx1, acc[mi][1][r]) : mx1;
          }
        mx0 = fmaxf(mx0, __shfl_xor(mx0, 16));
        mx0 = fmaxf(mx0, __shfl_xor(mx0, 32));
        mx1 = fmaxf(mx1, __shfl_xor(mx1, 16));
        mx1 = fmaxf(mx1, __shfl_xor(mx1, 32));

        const int v = lvid[rs];
        const bool bd = (rs == 0) || (re == 64);
        if (l4 == 0) {
          unsigned* base = zu + (size_t)v * DMID + w * 32 + l15;
          const unsigned e0 = enc_max(mx0), e1 = enc_max(mx1);
          if (bd) { atomicMax(base, e0); atomicMax(base + 16, e1); }
          else    { base[0] = e0;        base[16] = e1; }
        }
        m = m2;
      }
    }
    __syncthreads();
  }
}

// ---------------------------------------------------------------------------
// Kernel Y: Y = unflip(zu) @ W2b  (V x 128). Block 256, wave 2x2.
// ---------------------------------------------------------------------------
__global__ __launch_bounds__(256) void k_ymm(
    const unsigned* __restrict__ zu, const float* __restrict__ W2,
    float* __restrict__ Y, int ntiles) {
  extern __shared__ unsigned short sm[];
  unsigned short* w2bt = sm;               // [128][264]
  unsigned short* za   = sm + 128 * 264;   // [64][264]

  const int tid  = threadIdx.x;
  const int lane = tid & 63;
  const int w    = tid >> 6;
  const int wr   = w >> 1, wc = w & 1;
  const int l15  = lane & 15, l4 = lane >> 4;

  {
    const int n = tid & 127, kh = tid >> 7;
    for (int k = kh * 128; k < kh * 128 + 128; ++k)
      w2bt[n * 264 + k] = f2b(W2[(size_t)(DIN + k) * DOUT + n]);
  }
  __syncthreads();

  for (int t = blockIdx.x; t < ntiles; t += gridDim.x) {
    {
      const int row = tid >> 2, q = tid & 3;
      const int v = t * 64 + row;
      unsigned short* dz = &za[row * 264 + q * 64];
      if (v < VNUM) {
        const uint4* sz = reinterpret_cast<const uint4*>(zu + (size_t)v * DMID + q * 64);
#pragma unroll
        for (int i = 0; i < 16; ++i) {
          uint4 m = sz[i];
          ushort4 o = { (unsigned short)(unflip_bits(m.x) >> 16),
                        (unsigned short)(unflip_bits(m.y) >> 16),
                        (unsigned short)(unflip_bits(m.z) >> 16),
                        (unsigned short)(unflip_bits(m.w) >> 16) };
          *reinterpret_cast<ushort4*>(dz + i * 4) = o;
        }
      } else {
        ushort4 zo = {0, 0, 0, 0};
#pragma unroll
        for (int i = 0; i < 16; ++i) *reinterpret_cast<ushort4*>(dz + i * 4) = zo;
      }
    }
    __syncthreads();

    f32x4 acc[2][4];
#pragma unroll
    for (int mi = 0; mi < 2; ++mi)
#pragma unroll
      for (int ni = 0; ni < 4; ++ni) acc[mi][ni] = (f32x4){0.f, 0.f, 0.f, 0.f};

#pragma unroll
    for (int kk = 0; kk < 8; ++kk) {
      bf16x8 a[2], b[4];
#pragma unroll
      for (int mi = 0; mi < 2; ++mi)
        a[mi] = *reinterpret_cast<const bf16x8*>(
            &za[(wr * 32 + mi * 16 + l15) * 264 + kk * 32 + l4 * 8]);
#pragma unroll
      for (int ni = 0; ni < 4; ++ni)
        b[ni] = *reinterpret_cast<const bf16x8*>(
            &w2bt[(wc * 64 + ni * 16 + l15) * 264 + kk * 32 + l4 * 8]);
#pragma unroll
      for (int mi = 0; mi < 2; ++mi)
#pragma unroll
        for (int ni = 0; ni < 4; ++ni)
          acc[mi][ni] = __builtin_amdgcn_mfma_f32_16x16x32_bf16(
              a[mi], b[ni], acc[mi][ni], 0, 0, 0);
    }

#pragma unroll
    for (int mi = 0; mi < 2; ++mi)
#pragma unroll
      for (int r = 0; r < 4; ++r) {
        const int v = t * 64 + wr * 32 + mi * 16 + l4 * 4 + r;
        if (v < VNUM) {
          float* o = Y + (size_t)v * DOUT + wc * 64 + l15;
#pragma unroll
          for (int ni = 0; ni < 4; ++ni) o[ni * 16] = acc[mi][ni][r];
        }
      }
    __syncthreads();
  }
}

// ---------------------------------------------------------------------------
// Kernel 2: out = x @ W2a + Y[vid]  (original edge order). Block 256, wave 2x2.
// ---------------------------------------------------------------------------
__global__ __launch_bounds__(256, 3) void k_gemm2(
    const float* __restrict__ x, const int* __restrict__ vid,
    const float* __restrict__ W2, const float* __restrict__ Y,
    float* __restrict__ out, int ntiles) {
  __shared__ unsigned short w2at[128 * 136];
  __shared__ unsigned short lx[64 * 136];
  __shared__ int lvid[64];

  const int tid  = threadIdx.x;
  const int lane = tid & 63;
  const int w    = tid >> 6;
  const int wr   = w >> 1, wc = w & 1;
  const int l15  = lane & 15, l4 = lane >> 4;

  {
    const int n = tid & 127, kh = tid >> 7;
    for (int k = kh * 64; k < kh * 64 + 64; ++k)
      w2at[n * 136 + k] = f2b(W2[(size_t)k * DOUT + n]);
  }
  __syncthreads();

  for (int t = blockIdx.x; t < ntiles; t += gridDim.x) {
    {
      const int row = tid >> 2, q = tid & 3;
      const float4* sx =
          reinterpret_cast<const float4*>(x + (size_t)(t * 64 + row) * DIN + q * 32);
      unsigned short* dx = &lx[row * 136 + q * 32];
#pragma unroll
      for (int i = 0; i < 8; ++i) {
        float4 v = sx[i];
        ushort4 o = { f2b(v.x), f2b(v.y), f2b(v.z), f2b(v.w) };
        *reinterpret_cast<ushort4*>(dx + i * 4) = o;
      }
      if (tid < 64) lvid[tid] = vid[t * 64 + tid];
    }
    __syncthreads();

    f32x4 acc[2][4];
#pragma unroll
    for (int mi = 0; mi < 2; ++mi)
#pragma unroll
      for (int ni = 0; ni < 4; ++ni) acc[mi][ni] = (f32x4){0.f, 0.f, 0.f, 0.f};

#pragma unroll
    for (int kk = 0; kk < 4; ++kk) {
      bf16x8 a[2], b[4];
#pragma unroll
      for (int mi = 0; mi < 2; ++mi)
        a[mi] = *reinterpret_cast<const bf16x8*>(
            &lx[(wr * 32 + mi * 16 + l15) * 136 + kk * 32 + l4 * 8]);
#pragma unroll
      for (int ni = 0; ni < 4; ++ni)
        b[ni] = *reinterpret_cast<const bf16x8*>(
            &w2at[(wc * 64 + ni * 16 + l15) * 136 + kk * 32 + l4 * 8]);
#pragma unroll
      for (int mi = 0; mi < 2; ++mi)
#pragma unroll
        for (int ni = 0; ni < 4; ++ni)
          acc[mi][ni] = __builtin_amdgcn_mfma_f32_16x16x32_bf16(
              a[mi], b[ni], acc[mi][ni], 0, 0, 0);
    }

    // epilogue: + Y[vid], fp32 store
#pragma unroll
    for (int mi = 0; mi < 2; ++mi)
#pragma unroll
      for (int r = 0; r < 4; ++r) {
        const int row = wr * 32 + mi * 16 + l4 * 4 + r;
        const float* Yr = Y + (size_t)lvid[row] * DOUT + wc * 64 + l15;
        float* o = out + (size_t)(t * 64 + row) * DOUT + wc * 64 + l15;
#pragma unroll
        for (int ni = 0; ni < 4; ++ni) o[ni * 16] = acc[mi][ni][r] + Yr[ni * 16];
      }
    __syncthreads();
  }
}

// ---------------------------------------------------------------------------
extern "C" void kernel_launch(void* const* d_in, const int* in_sizes, int n_in,
                              void* d_out, int out_size, void* d_ws, size_t ws_size,
                              hipStream_t stream) {
  const float* x   = (const float*)d_in[0];
  const int*   vid = (const int*)d_in[1];
  const float* W1  = (const float*)d_in[2];
  const float* b1  = (const float*)d_in[3];
  const float* W2  = (const float*)d_in[4];
  float* out = (float*)d_out;

  const int E = in_sizes[1];      // 800000 (divisible by 64)
  const int ntiles = E / 64;
  const int ntY = (VNUM + 63) / 64;   // 782

  char* ws = (char*)d_ws;
  unsigned* zu = (unsigned*)ws;                                    // V*256 u32
  int* cnt     = (int*)(ws + (size_t)VNUM * DMID * 4);             // V
  int* sorted  = (int*)(ws + (size_t)VNUM * DMID * 4 + VNUM * 4);  // E
  float* Y     = (float*)(ws + (size_t)VNUM * DMID * 4 + VNUM * 4 + (size_t)E * 4);

  hipMemsetAsync(zu, 0, (size_t)VNUM * DMID * 4 + VNUM * 4, stream);

  k_hist<<<(E + 255) / 256, 256, 0, stream>>>(vid, cnt, E);
  k_scan<<<1, 1024, 0, stream>>>(cnt, VNUM);
  k_scatter<<<(E + 255) / 256, 256, 0, stream>>>(vid, cnt, sorted, E);

  k_gemm1_max<<<2048, 512, 0, stream>>>(x, vid, sorted, W1, b1, zu, ntiles);

  const int smY = (128 * 264 + 64 * 264) * sizeof(unsigned short);
  hipFuncSetAttribute((const void*)k_ymm,
                      hipFuncAttributeMaxDynamicSharedMemorySize, smY);
  k_ymm<<<782, 256, smY, stream>>>(zu, W2, Y, ntY);

  k_gemm2<<<768, 256, 0, stream>>>(x, vid, W2, Y, out, ntiles);
}